// Round 16
// baseline (287.837 us; speedup 1.0000x reference)
//
#include <hip/hip_runtime.h>
#include <hip/hip_bf16.h>

typedef __attribute__((ext_vector_type(4))) float f32x4;
typedef __attribute__((ext_vector_type(8))) int i32x8;

#define T_TOK 1370
#define DDIM  768
#define SCV   1369   // valid tokens per slab
#define SCP   1408   // s slab padded rows (11*128)
#define MQP   1536   // q padded rows (6*256)
#define NB    8
#define NSLAB 32
#define NST   22     // s supertiles of 256 (4*1408/256)
#define NMT   6      // m tiles of 256

#define MEMFENCE asm volatile("" ::: "memory")
#define BARRIER  do { __builtin_amdgcn_s_barrier(); MEMFENCE; } while (0)
#define VMCNT0   asm volatile("s_waitcnt vmcnt(0)" ::: "memory")

#define GLOAD_LDS16(g, l)                                                     \
  __builtin_amdgcn_global_load_lds(                                           \
      (const __attribute__((address_space(1))) unsigned int*)(g),             \
      (__attribute__((address_space(3))) unsigned int*)(l), 16, 0, 0)

// One block per output row: mean over 3 layers -> l2norm -> fp8 e4m3 store.
// dst layout: [slabs][pad][768] fp8, rows >= 1369 zeroed. pad via gridDim.x.
extern "C" __global__ __launch_bounds__(192) void prep_kernel(
    const float* __restrict__ src, unsigned char* __restrict__ dst,
    size_t lstride)
{
  const int row  = blockIdx.x;
  const int slab = blockIdx.y;
  const int t    = threadIdx.x;  // 0..191, each owns one float4 (768 = 192*4)
  unsigned char* drow = dst + ((size_t)slab * gridDim.x + row) * DDIM;
  if (row >= SCV) {
    reinterpret_cast<unsigned int*>(drow)[t] = 0u;
    return;
  }
  const float* base = src + ((size_t)slab * T_TOK + row + 1) * DDIM;
  float4 a = reinterpret_cast<const float4*>(base)[t];
  float4 b = reinterpret_cast<const float4*>(base + lstride)[t];
  float4 c = reinterpret_cast<const float4*>(base + 2 * lstride)[t];
  const float k3 = 1.0f / 3.0f;
  float4 m;
  m.x = (a.x + b.x + c.x) * k3;
  m.y = (a.y + b.y + c.y) * k3;
  m.z = (a.z + b.z + c.z) * k3;
  m.w = (a.w + b.w + c.w) * k3;
  float ss = m.x * m.x + m.y * m.y + m.z * m.z + m.w * m.w;
  #pragma unroll
  for (int d = 1; d < 64; d <<= 1) ss += __shfl_xor(ss, d);
  __shared__ float wsum[3];
  if ((t & 63) == 0) wsum[t >> 6] = ss;
  __syncthreads();
  float tot = wsum[0] + wsum[1] + wsum[2];
  float rn = 1.0f / fmaxf(sqrtf(tot), 1e-12f);
  int pk = __builtin_amdgcn_cvt_pk_fp8_f32(m.x * rn, m.y * rn, 0, false);
  pk = __builtin_amdgcn_cvt_pk_fp8_f32(m.z * rn, m.w * rn, pk, true);
  reinterpret_cast<unsigned int*>(drow)[t] = (unsigned int)pk;
}

// 256x256 tile, BK=128, MX-fp8 16x16x128 (scale=1.0), 16 waves (4M x 4N,
// per-wave 64x64 = 4x4 frags), dbuf LDS 2x64 KB, 6 K-steps, 4 waves/SIMD.
// Grid 1056 = 8 XCD-chunks x 132. part: [8][22][1536] float.
extern "C" __global__ __launch_bounds__(1024, 4) void simmax_kernel(
    const unsigned char* __restrict__ xq,
    const unsigned char* __restrict__ xs,
    float* __restrict__ part)
{
  // XCD-chunked bijective remap: nwg = 1056 = 8*132; XCD k owns batch n=k,
  // mt varies fastest so 6 consecutive blocks share one B supertile.
  const int flat = blockIdx.x;
  const int swz  = (flat & 7) * (NMT * NST) + (flat >> 3);
  const int n    = swz / (NMT * NST);
  const int idx  = swz - n * (NMT * NST);
  const int mt   = idx % NMT;
  const int st   = idx / NMT;

  const int tid  = threadIdx.x;  // 0..1023
  const int lane = tid & 63;
  const int w    = tid >> 6;     // 0..15
  const int wr   = w >> 2;       // 0..3 : 64-row quarter of 256
  const int wcn  = w & 3;        // 0..3 : 64-col quarter of 256
  const int l15  = lane & 15, l4 = lane >> 4;

  __shared__ unsigned char dbuf[2][65536];  // A 32 KB | B 32 KB per buffer
  __shared__ float sfold[1024];

  const unsigned char* gA = xq + ((size_t)n * MQP + (size_t)mt * 256) * DDIM;
  const unsigned char* gB = xs + ((size_t)n * 4 * SCP + (size_t)st * 256) * DDIM;

  // staging: A and B each 32 chunks of 1 KB (8 rows x 128 B); wave owns
  // chunks 2w, 2w+1 of each. lane -> row c*8+(lane>>3), 16-B slot lane&7.
  // Source pre-swizzled slot^(row&7); LDS dest linear; reads XOR the same
  // involution. 4 loads/thread per K-step.
  int goff[2], aldso[2], bldso[2];
  #pragma unroll
  for (int i = 0; i < 2; ++i) {
    int c = w * 2 + i;
    int r = c * 8 + (lane >> 3);
    goff[i]  = r * DDIM + (((lane & 7) ^ (r & 7)) << 4);
    aldso[i] = c * 1024;
    bldso[i] = 32768 + c * 1024;
  }

  // fragment read byte offsets: two b128 at off and off^16 per 32-B frag.
  int aoff[4], boff[4];
  #pragma unroll
  for (int mf = 0; mf < 4; ++mf) {
    int row = wr * 64 + mf * 16 + l15;
    aoff[mf] = row * 128 + ((((l4 << 1) ^ (row & 7))) << 4);
  }
  #pragma unroll
  for (int nf = 0; nf < 4; ++nf) {
    int row = wcn * 64 + nf * 16 + l15;
    boff[nf] = 32768 + row * 128 + ((((l4 << 1) ^ (row & 7))) << 4);
  }

  f32x4 acc[4][4];
  {
    f32x4 zz = {0.f, 0.f, 0.f, 0.f};
    #pragma unroll
    for (int a = 0; a < 4; ++a)
      #pragma unroll
      for (int b = 0; b < 4; ++b) acc[a][b] = zz;
  }

  #define ISSUE(KT, RB)                                                      \
    do {                                                                     \
      const unsigned char* ga_ = gA + (KT) * 128;                            \
      const unsigned char* gb_ = gB + (KT) * 128;                            \
      unsigned char* lb_ = dbuf[RB];                                         \
      _Pragma("unroll") for (int i = 0; i < 2; ++i)                          \
        GLOAD_LDS16(ga_ + goff[i], lb_ + aldso[i]);                          \
      _Pragma("unroll") for (int i = 0; i < 2; ++i)                          \
        GLOAD_LDS16(gb_ + goff[i], lb_ + bldso[i]);                          \
    } while (0)

  #define READ_FRAG(PTR, OFF, DST)                                           \
    do {                                                                     \
      int4 lo_ = *reinterpret_cast<const int4*>((PTR) + (OFF));              \
      int4 hi_ = *reinterpret_cast<const int4*>((PTR) + ((OFF) ^ 16));       \
      DST = i32x8{lo_.x, lo_.y, lo_.z, lo_.w, hi_.x, hi_.y, hi_.z, hi_.w};   \
    } while (0)

  ISSUE(0, 0);
  VMCNT0;
  BARRIER;

  for (int kt = 0; kt < 6; ++kt) {
    if (kt + 1 < 6) ISSUE(kt + 1, (kt + 1) & 1);

    const char* Cb = reinterpret_cast<const char*>(dbuf[kt & 1]);
    i32x8 af[4];
    #pragma unroll
    for (int mf = 0; mf < 4; ++mf) READ_FRAG(Cb, aoff[mf], af[mf]);

    __builtin_amdgcn_s_setprio(1);
    #pragma unroll
    for (int nf = 0; nf < 4; ++nf) {
      i32x8 bf;
      READ_FRAG(Cb, boff[nf], bf);
      #pragma unroll
      for (int mf = 0; mf < 4; ++mf)
        acc[mf][nf] = __builtin_amdgcn_mfma_scale_f32_16x16x128_f8f6f4(
            af[mf], bf, acc[mf][nf], 0, 0, 0, 127, 0, 127);
    }
    __builtin_amdgcn_s_setprio(0);

    if (kt + 1 < 6) VMCNT0;   // next buffer landed (issued a full step ago)
    if (kt < 5) BARRIER;
  }

  // ---- epilogue: masked running max, butterfly over 16 col-lanes ----
  bool colv[4];
  #pragma unroll
  for (int nf = 0; nf < 4; ++nf) {
    int col = st * 256 + wcn * 64 + nf * 16 + l15;   // 0..5631
    int within = col - (col / SCP) * SCP;
    colv[nf] = within < SCV;
  }

  float rm[4][4];
  #pragma unroll
  for (int mf = 0; mf < 4; ++mf)
    #pragma unroll
    for (int j = 0; j < 4; ++j) {
      float v = -1e30f;
      #pragma unroll
      for (int nf = 0; nf < 4; ++nf)
        if (colv[nf]) v = fmaxf(v, acc[mf][nf][j]);
      rm[mf][j] = v;
    }

  #pragma unroll
  for (int msk = 1; msk < 16; msk <<= 1)
    #pragma unroll
    for (int mf = 0; mf < 4; ++mf)
      #pragma unroll
      for (int j = 0; j < 4; ++j)
        rm[mf][j] = fmaxf(rm[mf][j], __shfl_xor(rm[mf][j], msk));

  __syncthreads();
  if (l15 == 0) {
    #pragma unroll
    for (int mf = 0; mf < 4; ++mf)
      #pragma unroll
      for (int j = 0; j < 4; ++j) {
        int r = wr * 64 + mf * 16 + l4 * 4 + j;   // 0..255
        sfold[wcn * 256 + r] = rm[mf][j];
      }
  }
  __syncthreads();
  if (tid < 256) {
    float v = fmaxf(fmaxf(sfold[tid], sfold[256 + tid]),
                    fmaxf(sfold[512 + tid], sfold[768 + tid]));
    part[((size_t)n * NST + st) * MQP + (size_t)mt * 256 + tid] = v;
  }
}

extern "C" __global__ void finalize_kernel(const float* __restrict__ part,
                                           float* __restrict__ out) {
  int i = blockIdx.x * 256 + threadIdx.x;
  if (i >= NB * SCV) return;
  int n = i / SCV, q = i - n * SCV;
  const float* p = part + (size_t)n * NST * MQP + q;
  float m = p[0];
  #pragma unroll 4
  for (int g = 1; g < NST; ++g) m = fmaxf(m, p[(size_t)g * MQP]);
  out[i] = 1.0f - m;
}

extern "C" void kernel_launch(void* const* d_in, const int* in_sizes, int n_in,
                              void* d_out, int out_size, void* d_ws, size_t ws_size,
                              hipStream_t stream) {
  const float* q_feats = (const float*)d_in[0];  // (3, 8, 1370, 768) f32
  const float* s_feats = (const float*)d_in[1];  // (3, 32, 1370, 768) f32
  float* out = (float*)d_out;                    // (8, 1, 37, 37) f32

  char* ws = (char*)d_ws;
  const size_t xq_bytes = (size_t)NB * MQP * DDIM;     // 9,437,184 (fp8)
  const size_t xs_bytes = (size_t)NSLAB * SCP * DDIM;  // 34,603,008 (fp8)
  unsigned char* xq = (unsigned char*)ws;
  unsigned char* xs = (unsigned char*)(ws + xq_bytes);
  float* part       = (float*)(ws + xq_bytes + xs_bytes); // 8*22*1536 floats

  prep_kernel<<<dim3(MQP, NB), 192, 0, stream>>>(
      q_feats, xq, (size_t)NB * T_TOK * DDIM);
  prep_kernel<<<dim3(SCP, NSLAB), 192, 0, stream>>>(
      s_feats, xs, (size_t)NSLAB * T_TOK * DDIM);
  simmax_kernel<<<dim3(NB * NMT * NST), 1024, 0, stream>>>(xq, xs, part);
  finalize_kernel<<<dim3((NB * SCV + 255) / 256), 256, 0, stream>>>(part, out);
}

// Round 17
// 191.695 us; speedup vs baseline: 1.5015x; 1.5015x over previous
//
#include <hip/hip_runtime.h>
#include <hip/hip_bf16.h>

typedef __attribute__((ext_vector_type(4))) float f32x4;
typedef __attribute__((ext_vector_type(8))) int i32x8;

#define T_TOK 1370
#define DDIM  768
#define SCV   1369   // valid tokens per slab
#define SCP   1408   // s slab padded rows (11*128)
#define MQP   1536   // q padded rows (8*192)
#define NB    8
#define NSLAB 32
#define NST   22     // s supertiles of 256 (4*1408/256)
#define NMT   8      // m tiles of 192

#define MEMFENCE asm volatile("" ::: "memory")
#define BARRIER  do { __builtin_amdgcn_s_barrier(); MEMFENCE; } while (0)

#define GLOAD_LDS16(g, l)                                                     \
  __builtin_amdgcn_global_load_lds(                                           \
      (const __attribute__((address_space(1))) unsigned int*)(g),             \
      (__attribute__((address_space(3))) unsigned int*)(l), 16, 0, 0)

// One block per output row: mean over 3 layers -> l2norm -> fp8 e4m3 store.
// dst layout: [slabs][pad][768] fp8, rows >= 1369 zeroed. pad via gridDim.x.
extern "C" __global__ __launch_bounds__(192) void prep_kernel(
    const float* __restrict__ src, unsigned char* __restrict__ dst,
    size_t lstride)
{
  const int row  = blockIdx.x;
  const int slab = blockIdx.y;
  const int t    = threadIdx.x;  // 0..191, each owns one float4 (768 = 192*4)
  unsigned char* drow = dst + ((size_t)slab * gridDim.x + row) * DDIM;
  if (row >= SCV) {
    reinterpret_cast<unsigned int*>(drow)[t] = 0u;
    return;
  }
  const float* base = src + ((size_t)slab * T_TOK + row + 1) * DDIM;
  float4 a = reinterpret_cast<const float4*>(base)[t];
  float4 b = reinterpret_cast<const float4*>(base + lstride)[t];
  float4 c = reinterpret_cast<const float4*>(base + 2 * lstride)[t];
  const float k3 = 1.0f / 3.0f;
  float4 m;
  m.x = (a.x + b.x + c.x) * k3;
  m.y = (a.y + b.y + c.y) * k3;
  m.z = (a.z + b.z + c.z) * k3;
  m.w = (a.w + b.w + c.w) * k3;
  float ss = m.x * m.x + m.y * m.y + m.z * m.z + m.w * m.w;
  #pragma unroll
  for (int d = 1; d < 64; d <<= 1) ss += __shfl_xor(ss, d);
  __shared__ float wsum[3];
  if ((t & 63) == 0) wsum[t >> 6] = ss;
  __syncthreads();
  float tot = wsum[0] + wsum[1] + wsum[2];
  float rn = 1.0f / fmaxf(sqrtf(tot), 1e-12f);
  int pk = __builtin_amdgcn_cvt_pk_fp8_f32(m.x * rn, m.y * rn, 0, false);
  pk = __builtin_amdgcn_cvt_pk_fp8_f32(m.z * rn, m.w * rn, pk, true);
  reinterpret_cast<unsigned int*>(drow)[t] = (unsigned int)pk;
}

// 192x256 tile, BK=128, MX-fp8 16x16x128 (scale=1.0), 8 waves (2M x 4N,
// per-wave 96x64 = 6x4 frags). A dbuf-2 (48 KB) + B ring-3 (96 KB) = 144 KB.
// Counted vmcnt(4): B(kt+2) stays in flight across the per-step barrier.
// Grid 1408 = 8 XCD-chunks x 176 (6 rounds of 0.75T vs 5 of T: less tail).
// part: [8][22][1536] float.
extern "C" __global__ __launch_bounds__(512, 2) void simmax_kernel(
    const unsigned char* __restrict__ xq,
    const unsigned char* __restrict__ xs,
    float* __restrict__ part)
{
  // XCD-chunked bijective remap: nwg = 1408 = 8*176; XCD k owns batch n=k,
  // mt varies fastest so 8 consecutive blocks share one B supertile.
  const int flat = blockIdx.x;
  const int swz  = (flat & 7) * (NMT * NST) + (flat >> 3);
  const int n    = swz / (NMT * NST);
  const int idx  = swz - n * (NMT * NST);
  const int mt   = idx % NMT;
  const int st   = idx / NMT;

  const int tid  = threadIdx.x;  // 0..511
  const int lane = tid & 63;
  const int w    = tid >> 6;     // 0..7
  const int wr   = w >> 2;       // 0..1 : 96-row half of 192
  const int wcn  = w & 3;        // 0..3 : 64-col quarter of 256
  const int l15  = lane & 15, l4 = lane >> 4;

  __shared__ unsigned char Abuf[2][24576];  // 48 KB (192 rows x 128 B each)
  __shared__ unsigned char Bbuf[3][32768];  // 96 KB (256 rows x 128 B each)

  const unsigned char* gA = xq + ((size_t)n * MQP + (size_t)mt * 192) * DDIM;
  const unsigned char* gB = xs + ((size_t)n * 4 * SCP + (size_t)st * 256) * DDIM;

  // staging: 1-KB chunks (8 rows x 128 B). A = 24 chunks (wave owns w*3..+2),
  // B = 32 chunks (wave owns w*4..+3). lane -> row c*8+(lane>>3), 16-B slot
  // lane&7. Source pre-swizzled slot^(row&7); LDS dest linear; reads XOR the
  // same involution.
  int agoff[3], aldso[3], bgoff[4], bldso[4];
  #pragma unroll
  for (int i = 0; i < 3; ++i) {
    int c = w * 3 + i;
    int r = c * 8 + (lane >> 3);
    agoff[i] = r * DDIM + (((lane & 7) ^ (r & 7)) << 4);
    aldso[i] = c * 1024;
  }
  #pragma unroll
  for (int i = 0; i < 4; ++i) {
    int c = w * 4 + i;
    int r = c * 8 + (lane >> 3);
    bgoff[i] = r * DDIM + (((lane & 7) ^ (r & 7)) << 4);
    bldso[i] = c * 1024;
  }

  // fragment read byte offsets: two b128 at off and off^16 per 32-B frag.
  int aoff[6], boff[4];
  #pragma unroll
  for (int mf = 0; mf < 6; ++mf) {
    int row = wr * 96 + mf * 16 + l15;
    aoff[mf] = row * 128 + ((((l4 << 1) ^ (row & 7))) << 4);
  }
  #pragma unroll
  for (int nf = 0; nf < 4; ++nf) {
    int row = wcn * 64 + nf * 16 + l15;
    boff[nf] = row * 128 + ((((l4 << 1) ^ (row & 7))) << 4);
  }

  f32x4 acc[6][4];
  {
    f32x4 zz = {0.f, 0.f, 0.f, 0.f};
    #pragma unroll
    for (int a = 0; a < 6; ++a)
      #pragma unroll
      for (int b = 0; b < 4; ++b) acc[a][b] = zz;
  }

  #define ISSUE_A(KT)                                                        \
    do {                                                                     \
      const unsigned char* ga_ = gA + (KT) * 128;                            \
      unsigned char* la_ = Abuf[(KT) & 1];                                   \
      _Pragma("unroll") for (int i = 0; i < 3; ++i)                          \
        GLOAD_LDS16(ga_ + agoff[i], la_ + aldso[i]);                         \
    } while (0)
  #define ISSUE_B(KT)                                                        \
    do {                                                                     \
      const unsigned char* gb_ = gB + (KT) * 128;                            \
      unsigned char* lb_ = Bbuf[(KT) % 3];                                   \
      _Pragma("unroll") for (int i = 0; i < 4; ++i)                          \
        GLOAD_LDS16(gb_ + bgoff[i], lb_ + bldso[i]);                         \
    } while (0)

  #define READ_FRAG(PTR, OFF, DST)                                           \
    do {                                                                     \
      int4 lo_ = *reinterpret_cast<const int4*>((PTR) + (OFF));              \
      int4 hi_ = *reinterpret_cast<const int4*>((PTR) + ((OFF) ^ 16));       \
      DST = i32x8{lo_.x, lo_.y, lo_.z, lo_.w, hi_.x, hi_.y, hi_.z, hi_.w};   \
    } while (0)

  // prologue: A(0), B(0) (oldest 7), then B(1) (youngest 4); wait oldest 7.
  ISSUE_A(0);
  ISSUE_B(0);
  MEMFENCE;
  ISSUE_B(1);
  asm volatile("s_waitcnt vmcnt(4)" ::: "memory");
  BARRIER;

  for (int kt = 0; kt < 6; ++kt) {
    // top: A(kt+1) first (older), then B(kt+2) (stays youngest in flight)
    if (kt + 1 < 6) ISSUE_A(kt + 1);
    MEMFENCE;
    if (kt + 2 < 6) ISSUE_B(kt + 2);

    const char* Ab = reinterpret_cast<const char*>(Abuf[kt & 1]);
    const char* Bb = reinterpret_cast<const char*>(Bbuf[kt % 3]);
    i32x8 bfr[4], af[6];
    #pragma unroll
    for (int nf = 0; nf < 4; ++nf) READ_FRAG(Bb, boff[nf], bfr[nf]);
    #pragma unroll
    for (int mf = 0; mf < 6; ++mf) READ_FRAG(Ab, aoff[mf], af[mf]);

    __builtin_amdgcn_s_setprio(1);
    #pragma unroll
    for (int mf = 0; mf < 6; ++mf)
      #pragma unroll
      for (int nf = 0; nf < 4; ++nf)
        acc[mf][nf] = __builtin_amdgcn_mfma_scale_f32_16x16x128_f8f6f4(
            af[mf], bfr[nf], acc[mf][nf], 0, 0, 0, 127, 0, 127);
    __builtin_amdgcn_s_setprio(0);

    // counted wait: A(kt+1)+B(kt+1) landed, B(kt+2)'s 4 stay in flight.
    if (kt < 4)       asm volatile("s_waitcnt vmcnt(4)" ::: "memory");
    else if (kt == 4) asm volatile("s_waitcnt vmcnt(0)" ::: "memory");
    if (kt < 5) BARRIER;
  }

  // ---- epilogue: masked running max, butterfly over 16 col-lanes ----
  bool colv[4];
  #pragma unroll
  for (int nf = 0; nf < 4; ++nf) {
    int col = st * 256 + wcn * 64 + nf * 16 + l15;   // 0..5631
    int within = col - (col / SCP) * SCP;
    colv[nf] = within < SCV;
  }

  float rm[6][4];
  #pragma unroll
  for (int mf = 0; mf < 6; ++mf)
    #pragma unroll
    for (int j = 0; j < 4; ++j) {
      float v = -1e30f;
      #pragma unroll
      for (int nf = 0; nf < 4; ++nf)
        if (colv[nf]) v = fmaxf(v, acc[mf][nf][j]);
      rm[mf][j] = v;
    }

  #pragma unroll
  for (int msk = 1; msk < 16; msk <<= 1)
    #pragma unroll
    for (int mf = 0; mf < 6; ++mf)
      #pragma unroll
      for (int j = 0; j < 4; ++j)
        rm[mf][j] = fmaxf(rm[mf][j], __shfl_xor(rm[mf][j], msk));

  __syncthreads();
  float* sfold = reinterpret_cast<float*>(&Abuf[0][0]);  // 768 floats
  if (l15 == 0) {
    #pragma unroll
    for (int mf = 0; mf < 6; ++mf)
      #pragma unroll
      for (int j = 0; j < 4; ++j) {
        int r = wr * 96 + mf * 16 + l4 * 4 + j;   // 0..191
        sfold[wcn * 192 + r] = rm[mf][j];
      }
  }
  __syncthreads();
  if (tid < 192) {
    float v = fmaxf(fmaxf(sfold[tid], sfold[192 + tid]),
                    fmaxf(sfold[384 + tid], sfold[576 + tid]));
    part[((size_t)n * NST + st) * MQP + (size_t)mt * 192 + tid] = v;
  }
}

extern "C" __global__ void finalize_kernel(const float* __restrict__ part,
                                           float* __restrict__ out) {
  int i = blockIdx.x * 256 + threadIdx.x;
  if (i >= NB * SCV) return;
  int n = i / SCV, q = i - n * SCV;
  const float* p = part + (size_t)n * NST * MQP + q;
  float m = p[0];
  #pragma unroll 4
  for (int g = 1; g < NST; ++g) m = fmaxf(m, p[(size_t)g * MQP]);
  out[i] = 1.0f - m;
}

extern "C" void kernel_launch(void* const* d_in, const int* in_sizes, int n_in,
                              void* d_out, int out_size, void* d_ws, size_t ws_size,
                              hipStream_t stream) {
  const float* q_feats = (const float*)d_in[0];  // (3, 8, 1370, 768) f32
  const float* s_feats = (const float*)d_in[1];  // (3, 32, 1370, 768) f32
  float* out = (float*)d_out;                    // (8, 1, 37, 37) f32

  char* ws = (char*)d_ws;
  const size_t xq_bytes = (size_t)NB * MQP * DDIM;     // 9,437,184 (fp8)
  const size_t xs_bytes = (size_t)NSLAB * SCP * DDIM;  // 34,603,008 (fp8)
  unsigned char* xq = (unsigned char*)ws;
  unsigned char* xs = (unsigned char*)(ws + xq_bytes);
  float* part       = (float*)(ws + xq_bytes + xs_bytes); // 8*22*1536 floats

  prep_kernel<<<dim3(MQP, NB), 192, 0, stream>>>(
      q_feats, xq, (size_t)NB * T_TOK * DDIM);
  prep_kernel<<<dim3(SCP, NSLAB), 192, 0, stream>>>(
      s_feats, xs, (size_t)NSLAB * T_TOK * DDIM);
  simmax_kernel<<<dim3(NB * NMT * NST), 512, 0, stream>>>(xq, xs, part);
  finalize_kernel<<<dim3((NB * SCV + 255) / 256), 256, 0, stream>>>(part, out);
}

// Round 18
// 190.474 us; speedup vs baseline: 1.5112x; 1.0064x over previous
//
#include <hip/hip_runtime.h>
#include <hip/hip_bf16.h>

typedef __attribute__((ext_vector_type(4))) float f32x4;
typedef __attribute__((ext_vector_type(8))) int i32x8;

#define T_TOK 1370
#define DDIM  768
#define SCV   1369   // valid tokens per slab
#define SCP   1408   // s slab padded rows (11*128)
#define MQP   1536   // q padded rows (6*256)
#define NB    8
#define NSLAB 32
#define NST   22     // s supertiles of 256 (4*1408/256)
#define NMT   6      // m tiles of 256

#define MEMFENCE asm volatile("" ::: "memory")
#define BARRIER  do { __builtin_amdgcn_s_barrier(); MEMFENCE; } while (0)

#define GLOAD_LDS16(g, l)                                                     \
  __builtin_amdgcn_global_load_lds(                                           \
      (const __attribute__((address_space(1))) unsigned int*)(g),             \
      (__attribute__((address_space(3))) unsigned int*)(l), 16, 0, 0)

// Fused prep: blockIdx.y in [0,40): y<8 -> q slab y; else s slab y-8.
// mean over 3 layers -> l2norm -> fp8 e4m3. Rows >= SCV zeroed up to pad.
extern "C" __global__ __launch_bounds__(192) void prep_all_kernel(
    const float* __restrict__ qf, const float* __restrict__ sf,
    unsigned char* __restrict__ xq, unsigned char* __restrict__ xs)
{
  const int row = blockIdx.x;   // 0..1535
  const int sl  = blockIdx.y;   // 0..39
  const float* src;
  unsigned char* dst;
  size_t lstride;
  int pad;
  if (sl < NB) {
    src = qf + (size_t)sl * T_TOK * DDIM;
    dst = xq + (size_t)sl * MQP * DDIM;
    lstride = (size_t)NB * T_TOK * DDIM;
    pad = MQP;
  } else {
    const int s2 = sl - NB;
    src = sf + (size_t)s2 * T_TOK * DDIM;
    dst = xs + (size_t)s2 * SCP * DDIM;
    lstride = (size_t)NSLAB * T_TOK * DDIM;
    pad = SCP;
  }
  if (row >= pad) return;
  const int t = threadIdx.x;    // 0..191, one float4 each (768 = 192*4)
  unsigned char* drow = dst + (size_t)row * DDIM;
  if (row >= SCV) {
    reinterpret_cast<unsigned int*>(drow)[t] = 0u;
    return;
  }
  const float* base = src + (size_t)(row + 1) * DDIM;
  float4 a = reinterpret_cast<const float4*>(base)[t];
  float4 b = reinterpret_cast<const float4*>(base + lstride)[t];
  float4 c = reinterpret_cast<const float4*>(base + 2 * lstride)[t];
  const float k3 = 1.0f / 3.0f;
  float4 m;
  m.x = (a.x + b.x + c.x) * k3;
  m.y = (a.y + b.y + c.y) * k3;
  m.z = (a.z + b.z + c.z) * k3;
  m.w = (a.w + b.w + c.w) * k3;
  float ss = m.x * m.x + m.y * m.y + m.z * m.z + m.w * m.w;
  #pragma unroll
  for (int d = 1; d < 64; d <<= 1) ss += __shfl_xor(ss, d);
  __shared__ float wsum[3];
  if ((t & 63) == 0) wsum[t >> 6] = ss;
  __syncthreads();
  float tot = wsum[0] + wsum[1] + wsum[2];
  float rn = 1.0f / fmaxf(sqrtf(tot), 1e-12f);
  int pk = __builtin_amdgcn_cvt_pk_fp8_f32(m.x * rn, m.y * rn, 0, false);
  pk = __builtin_amdgcn_cvt_pk_fp8_f32(m.z * rn, m.w * rn, pk, true);
  reinterpret_cast<unsigned int*>(drow)[t] = (unsigned int)pk;
}

// 256x256 tile, BK=128, MX-fp8 16x16x128 (scale=1.0), 8 waves (2M x 4N,
// per-wave 128x64). A dbuf-2 (64 KB) + B ring-3 (96 KB) = 160 KiB.
// Counted vmcnt(4): B(kt+2) stays in flight across the per-step barrier.
// Single barrier per K-step (R11 schedule otherwise unchanged).
// Grid 1056 = 8 XCD-chunks x 132. part: [8][22][1536] float.
extern "C" __global__ __launch_bounds__(512, 2) void simmax_kernel(
    const unsigned char* __restrict__ xq,
    const unsigned char* __restrict__ xs,
    float* __restrict__ part)
{
  // XCD-chunked bijective remap: nwg = 1056 = 8*132; XCD k owns batch n=k,
  // mt varies fastest so 6 consecutive blocks share one B supertile.
  const int flat = blockIdx.x;
  const int swz  = (flat & 7) * (NMT * NST) + (flat >> 3);
  const int n    = swz / (NMT * NST);
  const int idx  = swz - n * (NMT * NST);
  const int mt   = idx % NMT;
  const int st   = idx / NMT;

  const int tid  = threadIdx.x;  // 0..511
  const int lane = tid & 63;
  const int w    = tid >> 6;     // 0..7
  const int wr   = w >> 2;       // 0..1 : 128-row half of 256
  const int wcn  = w & 3;        // 0..3 : 64-col quarter of 256
  const int l15  = lane & 15, l4 = lane >> 4;

  __shared__ unsigned char Abuf[2][32768];  //  64 KB
  __shared__ unsigned char Bbuf[3][32768];  //  96 KB  (160 KiB total)

  const unsigned char* gA = xq + ((size_t)n * MQP + (size_t)mt * 256) * DDIM;
  const unsigned char* gB = xs + ((size_t)n * 4 * SCP + (size_t)st * 256) * DDIM;

  // staging: A and B each 32 chunks of 1 KB (8 rows x 128 B); wave owns
  // chunks w*4..+3 of each. lane -> row c*8+(lane>>3), 16-B slot lane&7.
  // Source pre-swizzled slot^(row&7); LDS dest linear; reads XOR the same
  // involution.
  int goff[4], ldso[4];
  #pragma unroll
  for (int i = 0; i < 4; ++i) {
    int c = w * 4 + i;
    int r = c * 8 + (lane >> 3);
    goff[i] = r * DDIM + (((lane & 7) ^ (r & 7)) << 4);
    ldso[i] = c * 1024;
  }

  // fragment read byte offsets: two b128 at off and off^16 per 32-B frag.
  int aoff[8], boff[4];
  #pragma unroll
  for (int mf = 0; mf < 8; ++mf) {
    int row = wr * 128 + mf * 16 + l15;
    aoff[mf] = row * 128 + ((((l4 << 1) ^ (row & 7))) << 4);
  }
  #pragma unroll
  for (int nf = 0; nf < 4; ++nf) {
    int row = wcn * 64 + nf * 16 + l15;
    boff[nf] = row * 128 + ((((l4 << 1) ^ (row & 7))) << 4);
  }

  f32x4 acc[8][4];
  {
    f32x4 zz = {0.f, 0.f, 0.f, 0.f};
    #pragma unroll
    for (int a = 0; a < 8; ++a)
      #pragma unroll
      for (int b = 0; b < 4; ++b) acc[a][b] = zz;
  }

  #define ISSUE_A(KT)                                                        \
    do {                                                                     \
      const unsigned char* ga_ = gA + (KT) * 128;                            \
      unsigned char* la_ = Abuf[(KT) & 1];                                   \
      _Pragma("unroll") for (int i = 0; i < 4; ++i)                          \
        GLOAD_LDS16(ga_ + goff[i], la_ + ldso[i]);                           \
    } while (0)
  #define ISSUE_B(KT)                                                        \
    do {                                                                     \
      const unsigned char* gb_ = gB + (KT) * 128;                            \
      unsigned char* lb_ = Bbuf[(KT) % 3];                                   \
      _Pragma("unroll") for (int i = 0; i < 4; ++i)                          \
        GLOAD_LDS16(gb_ + goff[i], lb_ + ldso[i]);                           \
    } while (0)

  #define READ_FRAG(PTR, OFF, DST)                                           \
    do {                                                                     \
      int4 lo_ = *reinterpret_cast<const int4*>((PTR) + (OFF));              \
      int4 hi_ = *reinterpret_cast<const int4*>((PTR) + ((OFF) ^ 16));       \
      DST = i32x8{lo_.x, lo_.y, lo_.z, lo_.w, hi_.x, hi_.y, hi_.z, hi_.w};   \
    } while (0)

  // prologue: A(0)+B(0) (oldest 8), then B(1) (youngest 4); wait oldest 8.
  ISSUE_A(0);
  ISSUE_B(0);
  MEMFENCE;
  ISSUE_B(1);
  asm volatile("s_waitcnt vmcnt(4)" ::: "memory");
  BARRIER;

  for (int kt = 0; kt < 6; ++kt) {
    // top: A(kt+1) first (older in queue), then B(kt+2) (stays youngest)
    if (kt + 1 < 6) ISSUE_A(kt + 1);
    MEMFENCE;
    if (kt + 2 < 6) ISSUE_B(kt + 2);

    const char* Ab = reinterpret_cast<const char*>(Abuf[kt & 1]);
    const char* Bb = reinterpret_cast<const char*>(Bbuf[kt % 3]);
    i32x8 bfr[4];
    #pragma unroll
    for (int nf = 0; nf < 4; ++nf) READ_FRAG(Bb, boff[nf], bfr[nf]);

    __builtin_amdgcn_s_setprio(1);
    #pragma unroll
    for (int mf = 0; mf < 8; ++mf) {
      i32x8 af;
      READ_FRAG(Ab, aoff[mf], af);
      #pragma unroll
      for (int nf = 0; nf < 4; ++nf)
        acc[mf][nf] = __builtin_amdgcn_mfma_scale_f32_16x16x128_f8f6f4(
            af, bfr[nf], acc[mf][nf], 0, 0, 0, 127, 0, 127);
    }
    __builtin_amdgcn_s_setprio(0);

    // counted wait: A(kt+1)+B(kt+1) landed; B(kt+2)'s 4 stay in flight.
    if (kt < 4)       asm volatile("s_waitcnt vmcnt(4)" ::: "memory");
    else if (kt == 4) asm volatile("s_waitcnt vmcnt(0)" ::: "memory");
    if (kt < 5) BARRIER;
  }

  // ---- epilogue: masked running max, butterfly over 16 col-lanes ----
  bool colv[4];
  #pragma unroll
  for (int nf = 0; nf < 4; ++nf) {
    int col = st * 256 + wcn * 64 + nf * 16 + l15;   // 0..5631
    int within = col - (col / SCP) * SCP;
    colv[nf] = within < SCV;
  }

  float rm[8][4];
  #pragma unroll
  for (int mf = 0; mf < 8; ++mf)
    #pragma unroll
    for (int j = 0; j < 4; ++j) {
      float v = -1e30f;
      #pragma unroll
      for (int nf = 0; nf < 4; ++nf)
        if (colv[nf]) v = fmaxf(v, acc[mf][nf][j]);
      rm[mf][j] = v;
    }

  #pragma unroll
  for (int msk = 1; msk < 16; msk <<= 1)
    #pragma unroll
    for (int mf = 0; mf < 8; ++mf)
      #pragma unroll
      for (int j = 0; j < 4; ++j)
        rm[mf][j] = fmaxf(rm[mf][j], __shfl_xor(rm[mf][j], msk));

  __syncthreads();
  float* sfold = reinterpret_cast<float*>(&Abuf[0][0]);  // 1024 floats
  if (l15 == 0) {
    #pragma unroll
    for (int mf = 0; mf < 8; ++mf)
      #pragma unroll
      for (int j = 0; j < 4; ++j) {
        int r = wr * 128 + mf * 16 + l4 * 4 + j;   // 0..255
        sfold[wcn * 256 + r] = rm[mf][j];
      }
  }
  __syncthreads();
  if (tid < 256) {
    float v = fmaxf(fmaxf(sfold[tid], sfold[256 + tid]),
                    fmaxf(sfold[512 + tid], sfold[768 + tid]));
    part[((size_t)n * NST + st) * MQP + (size_t)mt * 256 + tid] = v;
  }
}

extern "C" __global__ void finalize_kernel(const float* __restrict__ part,
                                           float* __restrict__ out) {
  int i = blockIdx.x * 256 + threadIdx.x;
  if (i >= NB * SCV) return;
  int n = i / SCV, q = i - n * SCV;
  const float* p = part + (size_t)n * NST * MQP + q;
  float m = p[0];
  #pragma unroll 4
  for (int g = 1; g < NST; ++g) m = fmaxf(m, p[(size_t)g * MQP]);
  out[i] = 1.0f - m;
}

extern "C" void kernel_launch(void* const* d_in, const int* in_sizes, int n_in,
                              void* d_out, int out_size, void* d_ws, size_t ws_size,
                              hipStream_t stream) {
  const float* q_feats = (const float*)d_in[0];  // (3, 8, 1370, 768) f32
  const float* s_feats = (const float*)d_in[1];  // (3, 32, 1370, 768) f32
  float* out = (float*)d_out;                    // (8, 1, 37, 37) f32

  char* ws = (char*)d_ws;
  const size_t xq_bytes = (size_t)NB * MQP * DDIM;     // 9,437,184 (fp8)
  const size_t xs_bytes = (size_t)NSLAB * SCP * DDIM;  // 34,603,008 (fp8)
  unsigned char* xq = (unsigned char*)ws;
  unsigned char* xs = (unsigned char*)(ws + xq_bytes);
  float* part       = (float*)(ws + xq_bytes + xs_bytes); // 8*22*1536 floats

  prep_all_kernel<<<dim3(MQP, NB + NSLAB), 192, 0, stream>>>(
      q_feats, s_feats, xq, xs);
  simmax_kernel<<<dim3(NB * NMT * NST), 512, 0, stream>>>(xq, xs, part);
  finalize_kernel<<<dim3((NB * SCV + 255) / 256), 256, 0, stream>>>(part, out);
}

// Round 19
// 182.807 us; speedup vs baseline: 1.5745x; 1.0419x over previous
//
#include <hip/hip_runtime.h>
#include <hip/hip_bf16.h>

typedef __attribute__((ext_vector_type(4))) float f32x4;
typedef __attribute__((ext_vector_type(8))) int i32x8;

#define T_TOK 1370
#define DDIM  768
#define SCV   1369   // valid tokens per slab
#define SCP   1408   // s slab padded rows (11*128)
#define MQP   1536   // q padded rows (6*256)
#define NB    8
#define NSLAB 32
#define NST   22     // s supertiles of 256 (4*1408/256)
#define NMT   6      // m tiles of 256

#define MEMFENCE asm volatile("" ::: "memory")
#define BARRIER  do { __builtin_amdgcn_s_barrier(); MEMFENCE; } while (0)
#define VMCNT0   asm volatile("s_waitcnt vmcnt(0)" ::: "memory")

#define GLOAD_LDS16(g, l)                                                     \
  __builtin_amdgcn_global_load_lds(                                           \
      (const __attribute__((address_space(1))) unsigned int*)(g),             \
      (__attribute__((address_space(3))) unsigned int*)(l), 16, 0, 0)

// One block per output row: mean over 3 layers -> l2norm -> fp8 e4m3 store.
// dst layout: [slabs][pad][768] fp8, rows >= 1369 zeroed. pad via gridDim.x.
extern "C" __global__ __launch_bounds__(192) void prep_kernel(
    const float* __restrict__ src, unsigned char* __restrict__ dst,
    size_t lstride)
{
  const int row  = blockIdx.x;
  const int slab = blockIdx.y;
  const int t    = threadIdx.x;  // 0..191, each owns one float4 (768 = 192*4)
  unsigned char* drow = dst + ((size_t)slab * gridDim.x + row) * DDIM;
  if (row >= SCV) {
    reinterpret_cast<unsigned int*>(drow)[t] = 0u;
    return;
  }
  const float* base = src + ((size_t)slab * T_TOK + row + 1) * DDIM;
  float4 a = reinterpret_cast<const float4*>(base)[t];
  float4 b = reinterpret_cast<const float4*>(base + lstride)[t];
  float4 c = reinterpret_cast<const float4*>(base + 2 * lstride)[t];
  const float k3 = 1.0f / 3.0f;
  float4 m;
  m.x = (a.x + b.x + c.x) * k3;
  m.y = (a.y + b.y + c.y) * k3;
  m.z = (a.z + b.z + c.z) * k3;
  m.w = (a.w + b.w + c.w) * k3;
  float ss = m.x * m.x + m.y * m.y + m.z * m.z + m.w * m.w;
  #pragma unroll
  for (int d = 1; d < 64; d <<= 1) ss += __shfl_xor(ss, d);
  __shared__ float wsum[3];
  if ((t & 63) == 0) wsum[t >> 6] = ss;
  __syncthreads();
  float tot = wsum[0] + wsum[1] + wsum[2];
  float rn = 1.0f / fmaxf(sqrtf(tot), 1e-12f);
  int pk = __builtin_amdgcn_cvt_pk_fp8_f32(m.x * rn, m.y * rn, 0, false);
  pk = __builtin_amdgcn_cvt_pk_fp8_f32(m.z * rn, m.w * rn, pk, true);
  reinterpret_cast<unsigned int*>(drow)[t] = (unsigned int)pk;
}

// 256x256 tile, BK=128, MX-fp8 (scale=1.0) 16x16x128 MFMA, 8 waves
// (2M x 4N, per-wave 128x64), dbuf LDS 2x64 KB, 6 K-steps.
// Grid 1056 = 8 XCD-chunks x 132. part: [8][22][1536] float.
extern "C" __global__ __launch_bounds__(512, 2) void simmax_kernel(
    const unsigned char* __restrict__ xq,
    const unsigned char* __restrict__ xs,
    float* __restrict__ part)
{
  // XCD-chunked bijective remap: nwg = 1056 = 8*132; XCD k owns batch n=k,
  // mt varies fastest so 6 consecutive blocks share one B supertile.
  const int flat = blockIdx.x;
  const int swz  = (flat & 7) * (NMT * NST) + (flat >> 3);
  const int n    = swz / (NMT * NST);
  const int idx  = swz - n * (NMT * NST);
  const int mt   = idx % NMT;
  const int st   = idx / NMT;

  const int tid  = threadIdx.x;  // 0..511
  const int lane = tid & 63;
  const int w    = tid >> 6;     // 0..7
  const int wr   = w >> 2;       // 0..1 : 128-row half of 256
  const int wcn  = w & 3;        // 0..3 : 64-col quarter of 256
  const int l15  = lane & 15, l4 = lane >> 4;

  // dbuf: [2] x (A 256x128B = 32 KB | B 256x128B = 32 KB) = 128 KB
  __shared__ unsigned char ring[2][65536];
  __shared__ float sfold[1024];

  const unsigned char* gA = xq + ((size_t)n * MQP + (size_t)mt * 256) * DDIM;
  const unsigned char* gB = xs + ((size_t)n * 4 * SCP + (size_t)st * 256) * DDIM;

  // staging: A and B each 32 chunks of 1 KB (8 rows x 128 B); wave owns
  // chunks w*4..+3 of each. lane -> row c*8+(lane>>3), 16-B slot lane&7.
  // Source pre-swizzled slot^(row&7); LDS dest linear (c*1024 + lane*16);
  // reads XOR the same involution. Same goff serves A and B.
  int goff[4], ldso[4];
  #pragma unroll
  for (int i = 0; i < 4; ++i) {
    int c = w * 4 + i;
    int r = c * 8 + (lane >> 3);
    goff[i] = r * DDIM + (((lane & 7) ^ (r & 7)) << 4);
    ldso[i] = c * 1024;
  }

  // fragment read byte offsets: lane covers row (l15-based), 32 B at
  // k0 = l4*32 -> two b128 at slot (2*l4)^(row&7) and that ^16.
  int aoff[8], boff[4];
  #pragma unroll
  for (int mf = 0; mf < 8; ++mf) {
    int row = wr * 128 + mf * 16 + l15;
    aoff[mf] = row * 128 + ((((l4 << 1) ^ (row & 7))) << 4);
  }
  #pragma unroll
  for (int nf = 0; nf < 4; ++nf) {
    int row = wcn * 64 + nf * 16 + l15;
    boff[nf] = 32768 + row * 128 + ((((l4 << 1) ^ (row & 7))) << 4);
  }

  f32x4 acc[8][4];
  {
    f32x4 zz = {0.f, 0.f, 0.f, 0.f};
    #pragma unroll
    for (int a = 0; a < 8; ++a)
      #pragma unroll
      for (int b = 0; b < 4; ++b) acc[a][b] = zz;
  }

  #define ISSUE(KT, RB)                                                      \
    do {                                                                     \
      const unsigned char* ga_ = gA + (KT) * 128;                            \
      const unsigned char* gb_ = gB + (KT) * 128;                            \
      unsigned char* la_ = ring[RB];                                         \
      unsigned char* lb_ = ring[RB] + 32768;                                 \
      _Pragma("unroll") for (int i = 0; i < 4; ++i)                          \
        GLOAD_LDS16(ga_ + goff[i], la_ + ldso[i]);                           \
      _Pragma("unroll") for (int i = 0; i < 4; ++i)                          \
        GLOAD_LDS16(gb_ + goff[i], lb_ + ldso[i]);                           \
    } while (0)

  ISSUE(0, 0);
  VMCNT0;
  BARRIER;

  for (int kt = 0; kt < 6; ++kt) {
    if (kt + 1 < 6) ISSUE(kt + 1, (kt + 1) & 1);

    const char* Cb = reinterpret_cast<const char*>(ring[kt & 1]);
    i32x8 bfr[4];
    #pragma unroll
    for (int nf = 0; nf < 4; ++nf) {
      int4 lo = *reinterpret_cast<const int4*>(Cb + boff[nf]);
      int4 hi = *reinterpret_cast<const int4*>(Cb + (boff[nf] ^ 16));
      bfr[nf] = i32x8{lo.x, lo.y, lo.z, lo.w, hi.x, hi.y, hi.z, hi.w};
    }
    __builtin_amdgcn_s_setprio(1);
    #pragma unroll
    for (int mf = 0; mf < 8; ++mf) {
      int4 lo = *reinterpret_cast<const int4*>(Cb + aoff[mf]);
      int4 hi = *reinterpret_cast<const int4*>(Cb + (aoff[mf] ^ 16));
      i32x8 af = i32x8{lo.x, lo.y, lo.z, lo.w, hi.x, hi.y, hi.z, hi.w};
      #pragma unroll
      for (int nf = 0; nf < 4; ++nf)
        acc[mf][nf] = __builtin_amdgcn_mfma_scale_f32_16x16x128_f8f6f4(
            af, bfr[nf], acc[mf][nf], 0, 0, 0, 127, 0, 127);
    }
    __builtin_amdgcn_s_setprio(0);

    if (kt + 1 < 6) VMCNT0;   // next buffer landed (issued a full step ago)
    if (kt < 5) BARRIER;
  }

  // ---- epilogue: masked running max, butterfly over 16 col-lanes ----
  bool colv[4];
  #pragma unroll
  for (int nf = 0; nf < 4; ++nf) {
    int col = st * 256 + wcn * 64 + nf * 16 + l15;   // 0..5631
    int within = col - (col / SCP) * SCP;
    colv[nf] = within < SCV;
  }

  float rm[8][4];
  #pragma unroll
  for (int mf = 0; mf < 8; ++mf)
    #pragma unroll
    for (int j = 0; j < 4; ++j) {
      float v = -1e30f;
      #pragma unroll
      for (int nf = 0; nf < 4; ++nf)
        if (colv[nf]) v = fmaxf(v, acc[mf][nf][j]);
      rm[mf][j] = v;
    }

  #pragma unroll
  for (int msk = 1; msk < 16; msk <<= 1)
    #pragma unroll
    for (int mf = 0; mf < 8; ++mf)
      #pragma unroll
      for (int j = 0; j < 4; ++j)
        rm[mf][j] = fmaxf(rm[mf][j], __shfl_xor(rm[mf][j], msk));

  __syncthreads();
  if (l15 == 0) {
    #pragma unroll
    for (int mf = 0; mf < 8; ++mf)
      #pragma unroll
      for (int j = 0; j < 4; ++j) {
        int r = wr * 128 + mf * 16 + l4 * 4 + j;   // 0..255
        sfold[wcn * 256 + r] = rm[mf][j];
      }
  }
  __syncthreads();
  if (tid < 256) {
    float v = fmaxf(fmaxf(sfold[tid], sfold[256 + tid]),
                    fmaxf(sfold[512 + tid], sfold[768 + tid]));
    part[((size_t)n * NST + st) * MQP + (size_t)mt * 256 + tid] = v;
  }
}

extern "C" __global__ void finalize_kernel(const float* __restrict__ part,
                                           float* __restrict__ out) {
  int i = blockIdx.x * 256 + threadIdx.x;
  if (i >= NB * SCV) return;
  int n = i / SCV, q = i - n * SCV;
  const float* p = part + (size_t)n * NST * MQP + q;
  float m = p[0];
  #pragma unroll 4
  for (int g = 1; g < NST; ++g) m = fmaxf(m, p[(size_t)g * MQP]);
  out[i] = 1.0f - m;
}

extern "C" void kernel_launch(void* const* d_in, const int* in_sizes, int n_in,
                              void* d_out, int out_size, void* d_ws, size_t ws_size,
                              hipStream_t stream) {
  const float* q_feats = (const float*)d_in[0];  // (3, 8, 1370, 768) f32
  const float* s_feats = (const float*)d_in[1];  // (3, 32, 1370, 768) f32
  float* out = (float*)d_out;                    // (8, 1, 37, 37) f32

  char* ws = (char*)d_ws;
  const size_t xq_bytes = (size_t)NB * MQP * DDIM;     // 9,437,184 (fp8)
  const size_t xs_bytes = (size_t)NSLAB * SCP * DDIM;  // 34,603,008 (fp8)
  unsigned char* xq = (unsigned char*)ws;
  unsigned char* xs = (unsigned char*)(ws + xq_bytes);
  float* part       = (float*)(ws + xq_bytes + xs_bytes); // 8*22*1536 floats

  prep_kernel<<<dim3(MQP, NB), 192, 0, stream>>>(
      q_feats, xq, (size_t)NB * T_TOK * DDIM);
  prep_kernel<<<dim3(SCP, NSLAB), 192, 0, stream>>>(
      s_feats, xs, (size_t)NSLAB * T_TOK * DDIM);
  simmax_kernel<<<dim3(NB * NMT * NST), 512, 0, stream>>>(xq, xs, part);
  finalize_kernel<<<dim3((NB * SCV + 255) / 256), 256, 0, stream>>>(part, out);
}